// Round 4
// baseline (9675.629 us; speedup 1.0000x reference)
//
#include <hip/hip_runtime.h>
#include <hip/hip_bf16.h>

#define S_LEN 40
#define NB    256
#define EDIM  1024
#define HDIM  1024

typedef __attribute__((ext_vector_type(8))) short bf16x8;
typedef __attribute__((ext_vector_type(4))) float f32x4;
typedef unsigned short u16;

__device__ __forceinline__ float b2f(u16 v) {
    return __uint_as_float(((unsigned int)v) << 16);
}
__device__ __forceinline__ u16 f2b(float f) {
    unsigned int u = __float_as_uint(f);
    return (u16)((u + 0x7FFFu + ((u >> 16) & 1u)) >> 16);
}
// split f into hi+lo bf16 pair (lo = rne(f - hi))
__device__ __forceinline__ void fsplit(float f, u16& hi, u16& lo) {
    hi = f2b(f);
    lo = f2b(f - b2f(hi));
}
__device__ __forceinline__ float sigm(float x) {
    x = fminf(fmaxf(x, -30.f), 30.f);
    return 1.f / (1.f + __expf(-x));
}
__device__ __forceinline__ float tanh_fast(float x) {
    x = fminf(fmaxf(x, -15.f), 15.f);
    float e = __expf(2.f * x);
    return (e - 1.f) / (e + 1.f);
}

// Layout-robust probe: A[i][k]=i, B[k][j]=1/32 -> D[i][j]=i regardless of
// fragment k-ordering. Derives each acc reg's (m,n) under either orientation.
__device__ __forceinline__ void probe_mn(int lane, int* mrow, int* ncol) {
    bf16x8 pa, pb;
    u16 iv = f2b((float)(lane & 15));
#pragma unroll
    for (int e = 0; e < 8; e++) { pa[e] = (short)iv; pb[e] = (short)0x3D00; }
    f32x4 pacc = {0, 0, 0, 0};
    pacc = __builtin_amdgcn_mfma_f32_16x16x32_bf16(pa, pb, pacc, 0, 0, 0);
#pragma unroll
    for (int r = 0; r < 4; r++) {
        int m = (int)(pacc[r] + 0.5f);
        int cg = ((lane >> 4) << 2) + r;
        mrow[r] = m;
        ncol[r] = (m == cg) ? (lane & 15) : cg;
    }
}

// ---------------- f32 -> (hi, lo) bf16 split, 4 elems/thread ---------------
__global__ __launch_bounds__(256) void k_split4(const float* __restrict__ src,
                                                u16* __restrict__ dhi,
                                                u16* __restrict__ dlo, int n4) {
    int i = blockIdx.x * 256 + threadIdx.x;
    if (i < n4) {
        float4 v = ((const float4*)src)[i];
        ushort4 h, l;
        fsplit(v.x, h.x, l.x); fsplit(v.y, h.y, l.y);
        fsplit(v.z, h.z, l.z); fsplit(v.w, h.w, l.w);
        ((ushort4*)dhi)[i] = h;
        ((ushort4*)dlo)[i] = l;
    }
}

// ---------------- f32 copy, 4 elems/thread ---------------------------------
__global__ __launch_bounds__(256) void k_copyf4(const float* __restrict__ src,
                                                float* __restrict__ dst, int n4) {
    int i = blockIdx.x * 256 + threadIdx.x;
    if (i < n4) ((float4*)dst)[i] = ((const float4*)src)[i];
}

// ---------------- embedding gather + split ---------------------------------
__global__ __launch_bounds__(256) void k_embed_split(const int* __restrict__ tok,
                                                     const float* __restrict__ emb,
                                                     u16* __restrict__ xh,
                                                     u16* __restrict__ xl) {
    int b = blockIdx.x;          // s*N + n
    int t = threadIdx.x;
    int token = tok[b];
    float4 v = ((const float4*)(emb + (size_t)token * EDIM))[t];
    ushort4 h, l;
    fsplit(v.x, h.x, l.x); fsplit(v.y, h.y, l.y);
    fsplit(v.z, h.z, l.z); fsplit(v.w, h.w, l.w);
    ((ushort4*)(xh + (size_t)b * EDIM))[t] = h;
    ((ushort4*)(xl + (size_t)b * EDIM))[t] = l;
}

#define MFMA3(acc, ah, al, bh, bl)                                          \
    acc = __builtin_amdgcn_mfma_f32_16x16x32_bf16(ah, bh, acc, 0, 0, 0);    \
    acc = __builtin_amdgcn_mfma_f32_16x16x32_bf16(ah, bl, acc, 0, 0, 0);    \
    acc = __builtin_amdgcn_mfma_f32_16x16x32_bf16(al, bh, acc, 0, 0, 0);

// ---------------- fused GRU cell (split-bf16 MFMA, f32 master h) -----------
// 6 waves: w in {0,1,2}: gi gate w = x@wih_g^T ; w in {3,4,5}: gh = h@whh_g^T
__global__ __launch_bounds__(384) void k_gru_cell(
    const u16* __restrict__ x_h, const u16* __restrict__ x_l,
    const u16* __restrict__ hp_h, const u16* __restrict__ hp_l,
    const float* __restrict__ hp_f,
    const u16* __restrict__ wih_h, const u16* __restrict__ wih_l,
    const u16* __restrict__ whh_h, const u16* __restrict__ whh_l,
    const float* __restrict__ bih, const float* __restrict__ bhh,
    u16* __restrict__ ho_h, u16* __restrict__ ho_l, float* __restrict__ ho_f,
    u16* __restrict__ o2_h, u16* __restrict__ o2_l, float* __restrict__ o2_f) {
    __shared__ float red[6 * 32 * 32];
    const int tid = threadIdx.x;
    const int w = tid >> 6;
    const int lane = tid & 63;
    const int rb = blockIdx.y * 32;   // batch rows
    const int cb = blockIdx.x * 32;   // h cols
    const int gate = (w >= 3) ? (w - 3) : w;
    const int r0 = lane & 15;
    const int kk0 = (lane >> 4) * 8;

    const u16* Ah = (w < 3) ? x_h : hp_h;
    const u16* Al = (w < 3) ? x_l : hp_l;
    const size_t boff = ((size_t)gate * HDIM + cb) * 1024;
    const u16* Bh = ((w < 3) ? wih_h : whh_h) + boff;
    const u16* Bl = ((w < 3) ? wih_l : whh_l) + boff;

    const size_t arow = (size_t)(rb + r0) * 1024 + kk0;
    const size_t brow = (size_t)r0 * 1024 + kk0;

    f32x4 acc00 = {0,0,0,0}, acc01 = {0,0,0,0}, acc10 = {0,0,0,0}, acc11 = {0,0,0,0};

#pragma unroll 2
    for (int k = 0; k < 1024; k += 32) {
        bf16x8 a0h = *(const bf16x8*)(Ah + arow + k);
        bf16x8 a1h = *(const bf16x8*)(Ah + arow + 16 * 1024 + k);
        bf16x8 b0h = *(const bf16x8*)(Bh + brow + k);
        bf16x8 b1h = *(const bf16x8*)(Bh + brow + 16 * 1024 + k);
        bf16x8 a0l = *(const bf16x8*)(Al + arow + k);
        bf16x8 a1l = *(const bf16x8*)(Al + arow + 16 * 1024 + k);
        bf16x8 b0l = *(const bf16x8*)(Bl + brow + k);
        bf16x8 b1l = *(const bf16x8*)(Bl + brow + 16 * 1024 + k);
        MFMA3(acc00, a0h, a0l, b0h, b0l);
        MFMA3(acc01, a0h, a0l, b1h, b1l);
        MFMA3(acc10, a1h, a1l, b0h, b0l);
        MFMA3(acc11, a1h, a1l, b1h, b1l);
    }

    int mr[4], nc[4];
    probe_mn(lane, mr, nc);
    float* rw = red + w * 1024;
#pragma unroll
    for (int r = 0; r < 4; r++) {
        rw[mr[r] * 32 + nc[r]]              = acc00[r];
        rw[mr[r] * 32 + nc[r] + 16]         = acc01[r];
        rw[(mr[r] + 16) * 32 + nc[r]]       = acc10[r];
        rw[(mr[r] + 16) * 32 + nc[r] + 16]  = acc11[r];
    }
    __syncthreads();

    for (int i = tid; i < 1024; i += 384) {
        int rr = i >> 5, cc = i & 31;
        int col = cb + cc;
        int row = rb + rr;
        float gir = red[i], giz = red[1024 + i], gin = red[2048 + i];
        float ghr = red[3072 + i], ghz = red[4096 + i], ghn = red[5120 + i];
        float r = sigm(gir + bih[col] + ghr + bhh[col]);
        float z = sigm(giz + bih[HDIM + col] + ghz + bhh[HDIM + col]);
        float n = tanh_fast(gin + bih[2 * HDIM + col] +
                            r * (ghn + bhh[2 * HDIM + col]));
        float hp = hp_f[(size_t)row * HDIM + col];
        float hn2 = (1.f - z) * n + z * hp;
        size_t idx = (size_t)row * HDIM + col;
        u16 hh, hl;
        fsplit(hn2, hh, hl);
        ho_h[idx] = hh;
        ho_l[idx] = hl;
        ho_f[idx] = hn2;
        if (o2_h) { o2_h[idx] = hh; o2_l[idx] = hl; }
        if (o2_f) o2_f[idx] = hn2;
    }
}

// ---------------- fused attention step (one block per batch row) ------------
__global__ __launch_bounds__(256) void k_attn(
    const u16* __restrict__ xh, const u16* __restrict__ xl,
    const u16* __restrict__ h0h, const u16* __restrict__ h0l,
    const u16* __restrict__ h1h, const u16* __restrict__ h1l,
    const u16* __restrict__ awh, const u16* __restrict__ awl,
    const float* __restrict__ attn_b,
    const u16* __restrict__ ench, const u16* __restrict__ encl,
    u16* __restrict__ xcat_h, u16* __restrict__ xcat_l) {
    __shared__ float logit[S_LEN];
    __shared__ float awls[S_LEN];
    const int n = blockIdx.x;
    const int tid = threadIdx.x, w = tid >> 6, lane = tid & 63;
    const size_t nrow = (size_t)n * 1024;

    // phase 0: xcat[n][0:1024] = emb_t (dual)
    {
        ((ushort4*)(xcat_h + (size_t)n * 2048))[tid] =
            ((const ushort4*)(xh + nrow))[tid];
        ((ushort4*)(xcat_l + (size_t)n * 2048))[tid] =
            ((const ushort4*)(xl + nrow))[tid];
    }

    // phase 1: logits (f32 via hi+lo reconstruction)
#pragma unroll
    for (int si = 0; si < 10; si++) {
        int s = w * 10 + si;
        const u16* wrh = awh + (size_t)s * 3072;
        const u16* wrl = awl + (size_t)s * 3072;
        float acc = 0.f;
        for (int j = lane; j < 384; j += 64) {
            int off;
            const u16 *sh, *sl;
            if (j < 128)      { off = j << 3;          sh = xh + nrow;  sl = xl + nrow; }
            else if (j < 256) { off = (j - 128) << 3;  sh = h0h + nrow; sl = h0l + nrow; }
            else              { off = (j - 256) << 3;  sh = h1h + nrow; sl = h1l + nrow; }
            bf16x8 ah = *(const bf16x8*)(sh + off);
            bf16x8 al = *(const bf16x8*)(sl + off);
            bf16x8 bh = *(const bf16x8*)(wrh + (j << 3));
            bf16x8 bl = *(const bf16x8*)(wrl + (j << 3));
#pragma unroll
            for (int e = 0; e < 8; e++)
                acc = fmaf(b2f((u16)ah[e]) + b2f((u16)al[e]),
                           b2f((u16)bh[e]) + b2f((u16)bl[e]), acc);
        }
        for (int o = 32; o; o >>= 1) acc += __shfl_down(acc, o);
        if (lane == 0) logit[s] = acc + attn_b[s];
    }
    __syncthreads();

    // phase 2: softmax over S=40
    if (w == 0) {
        float v = (lane < S_LEN) ? logit[lane] : -1e30f;
        float m = v;
        for (int o = 32; o; o >>= 1) m = fmaxf(m, __shfl_xor(m, o));
        float e = (lane < S_LEN) ? __expf(v - m) : 0.f;
        float sum = e;
        for (int o = 32; o; o >>= 1) sum += __shfl_xor(sum, o);
        if (lane < S_LEN) awls[lane] = e / sum;
    }
    __syncthreads();

    // phase 3: applied context -> xcat[n][1024:2048] (dual)
    {
        int c4 = tid * 4;
        float a0 = 0, a1 = 0, a2 = 0, a3 = 0;
#pragma unroll
        for (int s = 0; s < S_LEN; s++) {
            float wgt = awls[s];
            size_t base = ((size_t)s * NB + n) << 10;
            ushort4 vh = *(const ushort4*)(ench + base + c4);
            ushort4 vl = *(const ushort4*)(encl + base + c4);
            a0 = fmaf(wgt, b2f(vh.x) + b2f(vl.x), a0);
            a1 = fmaf(wgt, b2f(vh.y) + b2f(vl.y), a1);
            a2 = fmaf(wgt, b2f(vh.z) + b2f(vl.z), a2);
            a3 = fmaf(wgt, b2f(vh.w) + b2f(vl.w), a3);
        }
        ushort4 oh, ol;
        fsplit(a0, oh.x, ol.x); fsplit(a1, oh.y, ol.y);
        fsplit(a2, oh.z, ol.z); fsplit(a3, oh.w, ol.w);
        *(ushort4*)(xcat_h + (size_t)n * 2048 + 1024 + c4) = oh;
        *(ushort4*)(xcat_l + (size_t)n * 2048 + 1024 + c4) = ol;
    }
}

// ---------------- comb GEMM: C = relu(A @ B^T + bias), split-bf16 ----------
__global__ __launch_bounds__(256) void k_comb(
    const u16* __restrict__ A_h, const u16* __restrict__ A_l,
    const u16* __restrict__ B_h, const u16* __restrict__ B_l,
    const float* __restrict__ bias,
    u16* __restrict__ C_h, u16* __restrict__ C_l) {
    __shared__ float red[4 * 32 * 32];
    const int tid = threadIdx.x, w = tid >> 6, lane = tid & 63;
    const int rb = blockIdx.y * 32, cb = blockIdx.x * 32;
    const int K = 2048;
    const int kbeg = w * 512;
    const int r0 = lane & 15, kk0 = (lane >> 4) * 8;

    f32x4 acc00 = {0,0,0,0}, acc01 = {0,0,0,0}, acc10 = {0,0,0,0}, acc11 = {0,0,0,0};
    const size_t aoff = (size_t)(rb + r0) * K + kbeg + kk0;
    const size_t boff = (size_t)(cb + r0) * K + kbeg + kk0;

#pragma unroll 2
    for (int k = 0; k < 512; k += 32) {
        bf16x8 a0h = *(const bf16x8*)(A_h + aoff + k);
        bf16x8 a1h = *(const bf16x8*)(A_h + aoff + 16 * K + k);
        bf16x8 b0h = *(const bf16x8*)(B_h + boff + k);
        bf16x8 b1h = *(const bf16x8*)(B_h + boff + 16 * K + k);
        bf16x8 a0l = *(const bf16x8*)(A_l + aoff + k);
        bf16x8 a1l = *(const bf16x8*)(A_l + aoff + 16 * K + k);
        bf16x8 b0l = *(const bf16x8*)(B_l + boff + k);
        bf16x8 b1l = *(const bf16x8*)(B_l + boff + 16 * K + k);
        MFMA3(acc00, a0h, a0l, b0h, b0l);
        MFMA3(acc01, a0h, a0l, b1h, b1l);
        MFMA3(acc10, a1h, a1l, b0h, b0l);
        MFMA3(acc11, a1h, a1l, b1h, b1l);
    }

    int mr[4], nc[4];
    probe_mn(lane, mr, nc);
    float* rw = red + w * 1024;
#pragma unroll
    for (int r = 0; r < 4; r++) {
        rw[mr[r] * 32 + nc[r]]              = acc00[r];
        rw[mr[r] * 32 + nc[r] + 16]         = acc01[r];
        rw[(mr[r] + 16) * 32 + nc[r]]       = acc10[r];
        rw[(mr[r] + 16) * 32 + nc[r] + 16]  = acc11[r];
    }
    __syncthreads();

    for (int i = tid; i < 1024; i += 256) {
        float s = red[i] + red[1024 + i] + red[2048 + i] + red[3072 + i];
        int rr = i >> 5, cc = i & 31;
        s += bias[cb + cc];
        s = fmaxf(s, 0.f);
        u16 hh, hl;
        fsplit(s, hh, hl);
        size_t idx = (size_t)(rb + rr) * 1024 + cb + cc;
        C_h[idx] = hh;
        C_l[idx] = hl;
    }
}

extern "C" void kernel_launch(void* const* d_in, const int* in_sizes, int n_in,
                              void* d_out, int out_size, void* d_ws, size_t ws_size,
                              hipStream_t stream) {
    const int*   tokens   = (const int*)d_in[0];
    const float* hidden   = (const float*)d_in[1];
    const float* emb      = (const float*)d_in[2];
    const float* enc_wih  = (const float*)d_in[3];
    const float* enc_whh  = (const float*)d_in[4];
    const float* enc_bih  = (const float*)d_in[5];
    const float* enc_bhh  = (const float*)d_in[6];
    const float* dec_wih  = (const float*)d_in[7];
    const float* dec_whh  = (const float*)d_in[8];
    const float* dec_bih  = (const float*)d_in[9];
    const float* dec_bhh  = (const float*)d_in[10];
    const float* attn_w   = (const float*)d_in[11];
    const float* attn_b   = (const float*)d_in[12];
    const float* comb_w   = (const float*)d_in[13];
    const float* comb_b   = (const float*)d_in[14];
    float* out = (float*)d_out;

    const size_t NH = (size_t)NB * HDIM;             // 262144
    const size_t WSZ = (size_t)2 * 3 * HDIM * EDIM;  // 6291456

    // ---- workspace: f32 h master first, then bf16 dual regions ----
    float* hf = (float*)d_ws;                        // 4*NH f32
    u16* wp = (u16*)(hf + 4 * NH);
    u16 *w_eih_h = wp;  wp += WSZ;
    u16 *w_eih_l = wp;  wp += WSZ;
    u16 *w_ehh_h = wp;  wp += WSZ;
    u16 *w_ehh_l = wp;  wp += WSZ;
    u16 *w_dih_h = wp;  wp += WSZ;
    u16 *w_dih_l = wp;  wp += WSZ;
    u16 *w_dhh_h = wp;  wp += WSZ;
    u16 *w_dhh_l = wp;  wp += WSZ;
    u16 *w_comb_h = wp; wp += (size_t)HDIM * 2048;
    u16 *w_comb_l = wp; wp += (size_t)HDIM * 2048;
    u16 *w_attn_h = wp; wp += (size_t)S_LEN * 3072;
    u16 *w_attn_l = wp; wp += (size_t)S_LEN * 3072;
    u16 *xe_h = wp;     wp += (size_t)S_LEN * NB * EDIM;
    u16 *xe_l = wp;     wp += (size_t)S_LEN * NB * EDIM;
    u16 *enc_h = wp;    wp += (size_t)S_LEN * NH;
    u16 *enc_l = wp;    wp += (size_t)S_LEN * NH;
    u16 *hb_h = wp;     wp += 4 * NH;
    u16 *hb_l = wp;     wp += 4 * NH;
    u16 *xcat_h = wp;   wp += (size_t)NB * 2048;
    u16 *xcat_l = wp;   wp += (size_t)NB * 2048;
    u16 *xcur_h = wp;   wp += NH;
    u16 *xcur_l = wp;   wp += NH;

    u16* h0h[2] = { hb_h, hb_h + 2 * NH };
    u16* h1h[2] = { hb_h + NH, hb_h + 3 * NH };
    u16* h0l[2] = { hb_l, hb_l + 2 * NH };
    u16* h1l[2] = { hb_l + NH, hb_l + 3 * NH };
    float* h0f[2] = { hf, hf + 2 * NH };
    float* h1f[2] = { hf + NH, hf + 3 * NH };

    // ---- one-time conversions ----
    k_split4<<<(int)(WSZ / 4 / 256), 256, 0, stream>>>(enc_wih, w_eih_h, w_eih_l, (int)(WSZ / 4));
    k_split4<<<(int)(WSZ / 4 / 256), 256, 0, stream>>>(enc_whh, w_ehh_h, w_ehh_l, (int)(WSZ / 4));
    k_split4<<<(int)(WSZ / 4 / 256), 256, 0, stream>>>(dec_wih, w_dih_h, w_dih_l, (int)(WSZ / 4));
    k_split4<<<(int)(WSZ / 4 / 256), 256, 0, stream>>>(dec_whh, w_dhh_h, w_dhh_l, (int)(WSZ / 4));
    k_split4<<<(int)(HDIM * 2048 / 4 / 256), 256, 0, stream>>>(comb_w, w_comb_h, w_comb_l,
                                                               HDIM * 2048 / 4);
    k_split4<<<(S_LEN * 3072 / 4 + 255) / 256, 256, 0, stream>>>(attn_w, w_attn_h, w_attn_l,
                                                                 S_LEN * 3072 / 4);
    k_embed_split<<<S_LEN * NB, 256, 0, stream>>>(tokens, emb, xe_h, xe_l);
    k_split4<<<(int)(2 * NH / 4 / 256), 256, 0, stream>>>(hidden, hb_h, hb_l, (int)(2 * NH / 4));
    k_copyf4<<<(int)(2 * NH / 4 / 256), 256, 0, stream>>>(hidden, hf, (int)(2 * NH / 4));

    dim3 gridc(32, 8);
    // ---- encoder (rolling: both layers advance together per timestep) ----
    for (int t = 0; t < S_LEN; t++) {
        int p = t & 1;
        k_gru_cell<<<gridc, 384, 0, stream>>>(
            xe_h + (size_t)t * NB * EDIM, xe_l + (size_t)t * NB * EDIM,
            h0h[p], h0l[p], h0f[p],
            w_eih_h, w_eih_l, w_ehh_h, w_ehh_l, enc_bih, enc_bhh,
            h0h[p ^ 1], h0l[p ^ 1], h0f[p ^ 1],
            (u16*)nullptr, (u16*)nullptr, (float*)nullptr);
        k_gru_cell<<<gridc, 384, 0, stream>>>(
            h0h[p ^ 1], h0l[p ^ 1],
            h1h[p], h1l[p], h1f[p],
            w_eih_h + (size_t)3 * HDIM * EDIM, w_eih_l + (size_t)3 * HDIM * EDIM,
            w_ehh_h + (size_t)3 * HDIM * HDIM, w_ehh_l + (size_t)3 * HDIM * HDIM,
            enc_bih + 3 * HDIM, enc_bhh + 3 * HDIM,
            h1h[p ^ 1], h1l[p ^ 1], h1f[p ^ 1],
            enc_h + (size_t)t * NH, enc_l + (size_t)t * NH, (float*)nullptr);
    }
    // ---- decoder ----
    for (int t = 0; t < S_LEN; t++) {
        int p = t & 1;
        k_attn<<<NB, 256, 0, stream>>>(
            xe_h + (size_t)t * NB * EDIM, xe_l + (size_t)t * NB * EDIM,
            h0h[p], h0l[p], h1h[p], h1l[p],
            w_attn_h, w_attn_l, attn_b, enc_h, enc_l, xcat_h, xcat_l);
        k_comb<<<dim3(32, 8), 256, 0, stream>>>(xcat_h, xcat_l, w_comb_h, w_comb_l,
                                                comb_b, xcur_h, xcur_l);
        k_gru_cell<<<gridc, 384, 0, stream>>>(
            xcur_h, xcur_l,
            h0h[p], h0l[p], h0f[p],
            w_dih_h, w_dih_l, w_dhh_h, w_dhh_l, dec_bih, dec_bhh,
            h0h[p ^ 1], h0l[p ^ 1], h0f[p ^ 1],
            (u16*)nullptr, (u16*)nullptr, (float*)nullptr);
        k_gru_cell<<<gridc, 384, 0, stream>>>(
            h0h[p ^ 1], h0l[p ^ 1],
            h1h[p], h1l[p], h1f[p],
            w_dih_h + (size_t)3 * HDIM * HDIM, w_dih_l + (size_t)3 * HDIM * HDIM,
            w_dhh_h + (size_t)3 * HDIM * HDIM, w_dhh_l + (size_t)3 * HDIM * HDIM,
            dec_bih + 3 * HDIM, dec_bhh + 3 * HDIM,
            h1h[p ^ 1], h1l[p ^ 1], h1f[p ^ 1],
            (u16*)nullptr, (u16*)nullptr, out + (size_t)t * NH);
    }
    // ---- hT = [h0 final, h1 final] (parity 0 after 40 steps) ----
    k_copyf4<<<(int)(2 * NH / 4 / 256), 256, 0, stream>>>(
        hf, out + (size_t)S_LEN * NH, (int)(2 * NH / 4));
}

// Round 5
// 8809.449 us; speedup vs baseline: 1.0983x; 1.0983x over previous
//
#include <hip/hip_runtime.h>
#include <hip/hip_bf16.h>

#define S_LEN 40
#define NB    256
#define EDIM  1024
#define HDIM  1024

typedef __attribute__((ext_vector_type(8))) short bf16x8;
typedef __attribute__((ext_vector_type(4))) float f32x4;
typedef unsigned short u16;

__device__ __forceinline__ float b2f(u16 v) {
    return __uint_as_float(((unsigned int)v) << 16);
}
__device__ __forceinline__ u16 f2b(float f) {
    unsigned int u = __float_as_uint(f);
    return (u16)((u + 0x7FFFu + ((u >> 16) & 1u)) >> 16);
}
// split f into hi+lo bf16 pair (lo = rne(f - hi))
__device__ __forceinline__ void fsplit(float f, u16& hi, u16& lo) {
    hi = f2b(f);
    lo = f2b(f - b2f(hi));
}
__device__ __forceinline__ float sigm(float x) {
    x = fminf(fmaxf(x, -30.f), 30.f);
    return 1.f / (1.f + __expf(-x));
}
__device__ __forceinline__ float tanh_fast(float x) {
    x = fminf(fmaxf(x, -15.f), 15.f);
    float e = __expf(2.f * x);
    return (e - 1.f) / (e + 1.f);
}

// Layout-robust probe: A[i][k]=i, B[k][j]=1/32 -> D[i][j]=i regardless of
// fragment k-ordering. Derives each acc reg's (m,n) under either orientation.
__device__ __forceinline__ void probe_mn(int lane, int* mrow, int* ncol) {
    bf16x8 pa, pb;
    u16 iv = f2b((float)(lane & 15));
#pragma unroll
    for (int e = 0; e < 8; e++) { pa[e] = (short)iv; pb[e] = (short)0x3D00; }
    f32x4 pacc = {0, 0, 0, 0};
    pacc = __builtin_amdgcn_mfma_f32_16x16x32_bf16(pa, pb, pacc, 0, 0, 0);
#pragma unroll
    for (int r = 0; r < 4; r++) {
        int m = (int)(pacc[r] + 0.5f);
        int cg = ((lane >> 4) << 2) + r;
        mrow[r] = m;
        ncol[r] = (m == cg) ? (lane & 15) : cg;
    }
}

// ---------------- f32 -> (hi, lo) bf16 split, 4 elems/thread ---------------
__global__ __launch_bounds__(256) void k_split4(const float* __restrict__ src,
                                                u16* __restrict__ dhi,
                                                u16* __restrict__ dlo, int n4) {
    int i = blockIdx.x * 256 + threadIdx.x;
    if (i < n4) {
        float4 v = ((const float4*)src)[i];
        ushort4 h, l;
        fsplit(v.x, h.x, l.x); fsplit(v.y, h.y, l.y);
        fsplit(v.z, h.z, l.z); fsplit(v.w, h.w, l.w);
        ((ushort4*)dhi)[i] = h;
        ((ushort4*)dlo)[i] = l;
    }
}

// ---------------- f32 copy, 4 elems/thread ---------------------------------
__global__ __launch_bounds__(256) void k_copyf4(const float* __restrict__ src,
                                                float* __restrict__ dst, int n4) {
    int i = blockIdx.x * 256 + threadIdx.x;
    if (i < n4) ((float4*)dst)[i] = ((const float4*)src)[i];
}

// ---------------- embedding gather + split ---------------------------------
__global__ __launch_bounds__(256) void k_embed_split(const int* __restrict__ tok,
                                                     const float* __restrict__ emb,
                                                     u16* __restrict__ xh,
                                                     u16* __restrict__ xl) {
    int b = blockIdx.x;          // s*N + n
    int t = threadIdx.x;
    int token = tok[b];
    float4 v = ((const float4*)(emb + (size_t)token * EDIM))[t];
    ushort4 h, l;
    fsplit(v.x, h.x, l.x); fsplit(v.y, h.y, l.y);
    fsplit(v.z, h.z, l.z); fsplit(v.w, h.w, l.w);
    ((ushort4*)(xh + (size_t)b * EDIM))[t] = h;
    ((ushort4*)(xl + (size_t)b * EDIM))[t] = l;
}

#define MFMA3(acc, ah, al, bh, bl)                                          \
    acc = __builtin_amdgcn_mfma_f32_16x16x32_bf16(ah, bh, acc, 0, 0, 0);    \
    acc = __builtin_amdgcn_mfma_f32_16x16x32_bf16(ah, bl, acc, 0, 0, 0);    \
    acc = __builtin_amdgcn_mfma_f32_16x16x32_bf16(al, bh, acc, 0, 0, 0);

// ---------------- fused GRU cell (split-bf16 MFMA, f32 master h) -----------
// 12 waves: pair p = w>>1 in {0..5}: {gi_r,gi_z,gi_n,gh_r,gh_z,gh_n};
// kh = w&1 splits K=1024 in two 512 halves. LDS reduce of 12 partials.
__global__ __launch_bounds__(768) void k_gru_cell(
    const u16* __restrict__ x_h, const u16* __restrict__ x_l,
    const u16* __restrict__ hp_h, const u16* __restrict__ hp_l,
    const float* __restrict__ hp_f,
    const u16* __restrict__ wih_h, const u16* __restrict__ wih_l,
    const u16* __restrict__ whh_h, const u16* __restrict__ whh_l,
    const float* __restrict__ bih, const float* __restrict__ bhh,
    u16* __restrict__ ho_h, u16* __restrict__ ho_l, float* __restrict__ ho_f,
    u16* __restrict__ o2_h, u16* __restrict__ o2_l, float* __restrict__ o2_f) {
    __shared__ float red[12 * 32 * 32];
    const int tid = threadIdx.x;
    const int w = tid >> 6;           // 0..11
    const int lane = tid & 63;
    const int pair = w >> 1;          // 0..5
    const int kh = w & 1;             // K half
    const int rb = blockIdx.y * 32;   // batch rows
    const int cb = blockIdx.x * 32;   // h cols
    const int gate = (pair >= 3) ? (pair - 3) : pair;
    const int r0 = lane & 15;
    const int kk0 = (lane >> 4) * 8;

    const u16* Ah = (pair < 3) ? x_h : hp_h;
    const u16* Al = (pair < 3) ? x_l : hp_l;
    const size_t boff = ((size_t)gate * HDIM + cb) * 1024;
    const u16* Bh = ((pair < 3) ? wih_h : whh_h) + boff;
    const u16* Bl = ((pair < 3) ? wih_l : whh_l) + boff;

    const size_t arow = (size_t)(rb + r0) * 1024 + kk0 + kh * 512;
    const size_t brow = (size_t)r0 * 1024 + kk0 + kh * 512;

    f32x4 acc00 = {0,0,0,0}, acc01 = {0,0,0,0}, acc10 = {0,0,0,0}, acc11 = {0,0,0,0};

#pragma unroll 2
    for (int k = 0; k < 512; k += 32) {
        bf16x8 a0h = *(const bf16x8*)(Ah + arow + k);
        bf16x8 a1h = *(const bf16x8*)(Ah + arow + 16 * 1024 + k);
        bf16x8 b0h = *(const bf16x8*)(Bh + brow + k);
        bf16x8 b1h = *(const bf16x8*)(Bh + brow + 16 * 1024 + k);
        bf16x8 a0l = *(const bf16x8*)(Al + arow + k);
        bf16x8 a1l = *(const bf16x8*)(Al + arow + 16 * 1024 + k);
        bf16x8 b0l = *(const bf16x8*)(Bl + brow + k);
        bf16x8 b1l = *(const bf16x8*)(Bl + brow + 16 * 1024 + k);
        MFMA3(acc00, a0h, a0l, b0h, b0l);
        MFMA3(acc01, a0h, a0l, b1h, b1l);
        MFMA3(acc10, a1h, a1l, b0h, b0l);
        MFMA3(acc11, a1h, a1l, b1h, b1l);
    }

    int mr[4], nc[4];
    probe_mn(lane, mr, nc);
    float* rw = red + w * 1024;
#pragma unroll
    for (int r = 0; r < 4; r++) {
        rw[mr[r] * 32 + nc[r]]              = acc00[r];
        rw[mr[r] * 32 + nc[r] + 16]         = acc01[r];
        rw[(mr[r] + 16) * 32 + nc[r]]       = acc10[r];
        rw[(mr[r] + 16) * 32 + nc[r] + 16]  = acc11[r];
    }
    __syncthreads();

    for (int i = tid; i < 1024; i += 768) {
        int rr = i >> 5, cc = i & 31;
        int col = cb + cc;
        int row = rb + rr;
        float gir = red[i]         + red[1024 + i];
        float giz = red[2048 + i]  + red[3072 + i];
        float gin = red[4096 + i]  + red[5120 + i];
        float ghr = red[6144 + i]  + red[7168 + i];
        float ghz = red[8192 + i]  + red[9216 + i];
        float ghn = red[10240 + i] + red[11264 + i];
        float r = sigm(gir + bih[col] + ghr + bhh[col]);
        float z = sigm(giz + bih[HDIM + col] + ghz + bhh[HDIM + col]);
        float n = tanh_fast(gin + bih[2 * HDIM + col] +
                            r * (ghn + bhh[2 * HDIM + col]));
        float hp = hp_f[(size_t)row * HDIM + col];
        float hn2 = (1.f - z) * n + z * hp;
        size_t idx = (size_t)row * HDIM + col;
        u16 hh, hl;
        fsplit(hn2, hh, hl);
        ho_h[idx] = hh;
        ho_l[idx] = hl;
        ho_f[idx] = hn2;
        if (o2_h) { o2_h[idx] = hh; o2_l[idx] = hl; }
        if (o2_f) o2_f[idx] = hn2;
    }
}

// ---------------- fused attention step (one block per batch row) ------------
__global__ __launch_bounds__(512) void k_attn(
    const u16* __restrict__ xh, const u16* __restrict__ xl,
    const u16* __restrict__ h0h, const u16* __restrict__ h0l,
    const u16* __restrict__ h1h, const u16* __restrict__ h1l,
    const u16* __restrict__ awh, const u16* __restrict__ awl,
    const float* __restrict__ attn_b,
    const u16* __restrict__ ench, const u16* __restrict__ encl,
    u16* __restrict__ xcat_h, u16* __restrict__ xcat_l) {
    __shared__ float logit[S_LEN];
    __shared__ float awls[S_LEN];
    __shared__ float part[2 * 1024];
    const int n = blockIdx.x;
    const int tid = threadIdx.x, w = tid >> 6, lane = tid & 63;
    const size_t nrow = (size_t)n * 1024;

    // phase 0: xcat[n][0:1024] = emb_t (dual); 512 threads: h then l
    {
        int t2 = tid & 255;
        if (tid < 256)
            ((ushort4*)(xcat_h + (size_t)n * 2048))[t2] =
                ((const ushort4*)(xh + nrow))[t2];
        else
            ((ushort4*)(xcat_l + (size_t)n * 2048))[t2] =
                ((const ushort4*)(xl + nrow))[t2];
    }

    // phase 1: logits (f32 via hi+lo reconstruction), 8 waves x 5 rows
#pragma unroll
    for (int si = 0; si < 5; si++) {
        int s = w * 5 + si;
        const u16* wrh = awh + (size_t)s * 3072;
        const u16* wrl = awl + (size_t)s * 3072;
        float acc = 0.f;
        for (int j = lane; j < 384; j += 64) {
            int off;
            const u16 *sh, *sl;
            if (j < 128)      { off = j << 3;          sh = xh + nrow;  sl = xl + nrow; }
            else if (j < 256) { off = (j - 128) << 3;  sh = h0h + nrow; sl = h0l + nrow; }
            else              { off = (j - 256) << 3;  sh = h1h + nrow; sl = h1l + nrow; }
            bf16x8 ah = *(const bf16x8*)(sh + off);
            bf16x8 al = *(const bf16x8*)(sl + off);
            bf16x8 bh = *(const bf16x8*)(wrh + (j << 3));
            bf16x8 bl = *(const bf16x8*)(wrl + (j << 3));
#pragma unroll
            for (int e = 0; e < 8; e++)
                acc = fmaf(b2f((u16)ah[e]) + b2f((u16)al[e]),
                           b2f((u16)bh[e]) + b2f((u16)bl[e]), acc);
        }
        for (int o = 32; o; o >>= 1) acc += __shfl_down(acc, o);
        if (lane == 0) logit[s] = acc + attn_b[s];
    }
    __syncthreads();

    // phase 2: softmax over S=40
    if (w == 0) {
        float v = (lane < S_LEN) ? logit[lane] : -1e30f;
        float m = v;
        for (int o = 32; o; o >>= 1) m = fmaxf(m, __shfl_xor(m, o));
        float e = (lane < S_LEN) ? __expf(v - m) : 0.f;
        float sum = e;
        for (int o = 32; o; o >>= 1) sum += __shfl_xor(sum, o);
        if (lane < S_LEN) awls[lane] = e / sum;
    }
    __syncthreads();

    // phase 3: applied context -> xcat[n][1024:2048]; two s-halves + reduce
    {
        int g = tid >> 8;              // 0 or 1: s in [g*20, g*20+20)
        int c4 = (tid & 255) * 4;
        float a0 = 0, a1 = 0, a2 = 0, a3 = 0;
#pragma unroll
        for (int s2 = 0; s2 < 20; s2++) {
            int s = g * 20 + s2;
            float wgt = awls[s];
            size_t base = ((size_t)s * NB + n) << 10;
            ushort4 vh = *(const ushort4*)(ench + base + c4);
            ushort4 vl = *(const ushort4*)(encl + base + c4);
            a0 = fmaf(wgt, b2f(vh.x) + b2f(vl.x), a0);
            a1 = fmaf(wgt, b2f(vh.y) + b2f(vl.y), a1);
            a2 = fmaf(wgt, b2f(vh.z) + b2f(vl.z), a2);
            a3 = fmaf(wgt, b2f(vh.w) + b2f(vl.w), a3);
        }
        float* pg = part + g * 1024 + c4;
        pg[0] = a0; pg[1] = a1; pg[2] = a2; pg[3] = a3;
    }
    __syncthreads();
    if (tid < 256) {
        int c4 = tid * 4;
        ushort4 oh, ol;
        float a0 = part[c4]     + part[1024 + c4];
        float a1 = part[c4 + 1] + part[1024 + c4 + 1];
        float a2 = part[c4 + 2] + part[1024 + c4 + 2];
        float a3 = part[c4 + 3] + part[1024 + c4 + 3];
        fsplit(a0, oh.x, ol.x); fsplit(a1, oh.y, ol.y);
        fsplit(a2, oh.z, ol.z); fsplit(a3, oh.w, ol.w);
        *(ushort4*)(xcat_h + (size_t)n * 2048 + 1024 + c4) = oh;
        *(ushort4*)(xcat_l + (size_t)n * 2048 + 1024 + c4) = ol;
    }
}

// ---------------- comb GEMM: C = relu(A @ B^T + bias), split-bf16 ----------
// 8 waves split K=2048 into 256 each.
__global__ __launch_bounds__(512) void k_comb(
    const u16* __restrict__ A_h, const u16* __restrict__ A_l,
    const u16* __restrict__ B_h, const u16* __restrict__ B_l,
    const float* __restrict__ bias,
    u16* __restrict__ C_h, u16* __restrict__ C_l) {
    __shared__ float red[8 * 32 * 32];
    const int tid = threadIdx.x, w = tid >> 6, lane = tid & 63;
    const int rb = blockIdx.y * 32, cb = blockIdx.x * 32;
    const int K = 2048;
    const int kbeg = w * 256;
    const int r0 = lane & 15, kk0 = (lane >> 4) * 8;

    f32x4 acc00 = {0,0,0,0}, acc01 = {0,0,0,0}, acc10 = {0,0,0,0}, acc11 = {0,0,0,0};
    const size_t aoff = (size_t)(rb + r0) * K + kbeg + kk0;
    const size_t boff = (size_t)(cb + r0) * K + kbeg + kk0;

#pragma unroll 2
    for (int k = 0; k < 256; k += 32) {
        bf16x8 a0h = *(const bf16x8*)(A_h + aoff + k);
        bf16x8 a1h = *(const bf16x8*)(A_h + aoff + 16 * K + k);
        bf16x8 b0h = *(const bf16x8*)(B_h + boff + k);
        bf16x8 b1h = *(const bf16x8*)(B_h + boff + 16 * K + k);
        bf16x8 a0l = *(const bf16x8*)(A_l + aoff + k);
        bf16x8 a1l = *(const bf16x8*)(A_l + aoff + 16 * K + k);
        bf16x8 b0l = *(const bf16x8*)(B_l + boff + k);
        bf16x8 b1l = *(const bf16x8*)(B_l + boff + 16 * K + k);
        MFMA3(acc00, a0h, a0l, b0h, b0l);
        MFMA3(acc01, a0h, a0l, b1h, b1l);
        MFMA3(acc10, a1h, a1l, b0h, b0l);
        MFMA3(acc11, a1h, a1l, b1h, b1l);
    }

    int mr[4], nc[4];
    probe_mn(lane, mr, nc);
    float* rw = red + w * 1024;
#pragma unroll
    for (int r = 0; r < 4; r++) {
        rw[mr[r] * 32 + nc[r]]              = acc00[r];
        rw[mr[r] * 32 + nc[r] + 16]         = acc01[r];
        rw[(mr[r] + 16) * 32 + nc[r]]       = acc10[r];
        rw[(mr[r] + 16) * 32 + nc[r] + 16]  = acc11[r];
    }
    __syncthreads();

    for (int i = tid; i < 1024; i += 512) {
        float s = red[i] + red[1024 + i] + red[2048 + i] + red[3072 + i] +
                  red[4096 + i] + red[5120 + i] + red[6144 + i] + red[7168 + i];
        int rr = i >> 5, cc = i & 31;
        s += bias[cb + cc];
        s = fmaxf(s, 0.f);
        u16 hh, hl;
        fsplit(s, hh, hl);
        size_t idx = (size_t)(rb + rr) * 1024 + cb + cc;
        C_h[idx] = hh;
        C_l[idx] = hl;
    }
}

extern "C" void kernel_launch(void* const* d_in, const int* in_sizes, int n_in,
                              void* d_out, int out_size, void* d_ws, size_t ws_size,
                              hipStream_t stream) {
    const int*   tokens   = (const int*)d_in[0];
    const float* hidden   = (const float*)d_in[1];
    const float* emb      = (const float*)d_in[2];
    const float* enc_wih  = (const float*)d_in[3];
    const float* enc_whh  = (const float*)d_in[4];
    const float* enc_bih  = (const float*)d_in[5];
    const float* enc_bhh  = (const float*)d_in[6];
    const float* dec_wih  = (const float*)d_in[7];
    const float* dec_whh  = (const float*)d_in[8];
    const float* dec_bih  = (const float*)d_in[9];
    const float* dec_bhh  = (const float*)d_in[10];
    const float* attn_w   = (const float*)d_in[11];
    const float* attn_b   = (const float*)d_in[12];
    const float* comb_w   = (const float*)d_in[13];
    const float* comb_b   = (const float*)d_in[14];
    float* out = (float*)d_out;

    const size_t NH = (size_t)NB * HDIM;             // 262144
    const size_t WSZ = (size_t)2 * 3 * HDIM * EDIM;  // 6291456

    // ---- workspace: f32 h master first, then bf16 dual regions ----
    float* hf = (float*)d_ws;                        // 4*NH f32
    u16* wp = (u16*)(hf + 4 * NH);
    u16 *w_eih_h = wp;  wp += WSZ;
    u16 *w_eih_l = wp;  wp += WSZ;
    u16 *w_ehh_h = wp;  wp += WSZ;
    u16 *w_ehh_l = wp;  wp += WSZ;
    u16 *w_dih_h = wp;  wp += WSZ;
    u16 *w_dih_l = wp;  wp += WSZ;
    u16 *w_dhh_h = wp;  wp += WSZ;
    u16 *w_dhh_l = wp;  wp += WSZ;
    u16 *w_comb_h = wp; wp += (size_t)HDIM * 2048;
    u16 *w_comb_l = wp; wp += (size_t)HDIM * 2048;
    u16 *w_attn_h = wp; wp += (size_t)S_LEN * 3072;
    u16 *w_attn_l = wp; wp += (size_t)S_LEN * 3072;
    u16 *xe_h = wp;     wp += (size_t)S_LEN * NB * EDIM;
    u16 *xe_l = wp;     wp += (size_t)S_LEN * NB * EDIM;
    u16 *enc_h = wp;    wp += (size_t)S_LEN * NH;
    u16 *enc_l = wp;    wp += (size_t)S_LEN * NH;
    u16 *hb_h = wp;     wp += 4 * NH;
    u16 *hb_l = wp;     wp += 4 * NH;
    u16 *xcat_h = wp;   wp += (size_t)NB * 2048;
    u16 *xcat_l = wp;   wp += (size_t)NB * 2048;
    u16 *xcur_h = wp;   wp += NH;
    u16 *xcur_l = wp;   wp += NH;

    u16* h0h[2] = { hb_h, hb_h + 2 * NH };
    u16* h1h[2] = { hb_h + NH, hb_h + 3 * NH };
    u16* h0l[2] = { hb_l, hb_l + 2 * NH };
    u16* h1l[2] = { hb_l + NH, hb_l + 3 * NH };
    float* h0f[2] = { hf, hf + 2 * NH };
    float* h1f[2] = { hf + NH, hf + 3 * NH };

    // ---- one-time conversions ----
    k_split4<<<(int)(WSZ / 4 / 256), 256, 0, stream>>>(enc_wih, w_eih_h, w_eih_l, (int)(WSZ / 4));
    k_split4<<<(int)(WSZ / 4 / 256), 256, 0, stream>>>(enc_whh, w_ehh_h, w_ehh_l, (int)(WSZ / 4));
    k_split4<<<(int)(WSZ / 4 / 256), 256, 0, stream>>>(dec_wih, w_dih_h, w_dih_l, (int)(WSZ / 4));
    k_split4<<<(int)(WSZ / 4 / 256), 256, 0, stream>>>(dec_whh, w_dhh_h, w_dhh_l, (int)(WSZ / 4));
    k_split4<<<(int)(HDIM * 2048 / 4 / 256), 256, 0, stream>>>(comb_w, w_comb_h, w_comb_l,
                                                               HDIM * 2048 / 4);
    k_split4<<<(S_LEN * 3072 / 4 + 255) / 256, 256, 0, stream>>>(attn_w, w_attn_h, w_attn_l,
                                                                 S_LEN * 3072 / 4);
    k_embed_split<<<S_LEN * NB, 256, 0, stream>>>(tokens, emb, xe_h, xe_l);
    k_split4<<<(int)(2 * NH / 4 / 256), 256, 0, stream>>>(hidden, hb_h, hb_l, (int)(2 * NH / 4));
    k_copyf4<<<(int)(2 * NH / 4 / 256), 256, 0, stream>>>(hidden, hf, (int)(2 * NH / 4));

    dim3 gridc(32, 8);
    // ---- encoder (rolling: both layers advance together per timestep) ----
    for (int t = 0; t < S_LEN; t++) {
        int p = t & 1;
        k_gru_cell<<<gridc, 768, 0, stream>>>(
            xe_h + (size_t)t * NB * EDIM, xe_l + (size_t)t * NB * EDIM,
            h0h[p], h0l[p], h0f[p],
            w_eih_h, w_eih_l, w_ehh_h, w_ehh_l, enc_bih, enc_bhh,
            h0h[p ^ 1], h0l[p ^ 1], h0f[p ^ 1],
            (u16*)nullptr, (u16*)nullptr, (float*)nullptr);
        k_gru_cell<<<gridc, 768, 0, stream>>>(
            h0h[p ^ 1], h0l[p ^ 1],
            h1h[p], h1l[p], h1f[p],
            w_eih_h + (size_t)3 * HDIM * EDIM, w_eih_l + (size_t)3 * HDIM * EDIM,
            w_ehh_h + (size_t)3 * HDIM * HDIM, w_ehh_l + (size_t)3 * HDIM * HDIM,
            enc_bih + 3 * HDIM, enc_bhh + 3 * HDIM,
            h1h[p ^ 1], h1l[p ^ 1], h1f[p ^ 1],
            enc_h + (size_t)t * NH, enc_l + (size_t)t * NH, (float*)nullptr);
    }
    // ---- decoder ----
    for (int t = 0; t < S_LEN; t++) {
        int p = t & 1;
        k_attn<<<NB, 512, 0, stream>>>(
            xe_h + (size_t)t * NB * EDIM, xe_l + (size_t)t * NB * EDIM,
            h0h[p], h0l[p], h1h[p], h1l[p],
            w_attn_h, w_attn_l, attn_b, enc_h, enc_l, xcat_h, xcat_l);
        k_comb<<<dim3(32, 8), 512, 0, stream>>>(xcat_h, xcat_l, w_comb_h, w_comb_l,
                                                comb_b, xcur_h, xcur_l);
        k_gru_cell<<<gridc, 768, 0, stream>>>(
            xcur_h, xcur_l,
            h0h[p], h0l[p], h0f[p],
            w_dih_h, w_dih_l, w_dhh_h, w_dhh_l, dec_bih, dec_bhh,
            h0h[p ^ 1], h0l[p ^ 1], h0f[p ^ 1],
            (u16*)nullptr, (u16*)nullptr, (float*)nullptr);
        k_gru_cell<<<gridc, 768, 0, stream>>>(
            h0h[p ^ 1], h0l[p ^ 1],
            h1h[p], h1l[p], h1f[p],
            w_dih_h + (size_t)3 * HDIM * HDIM, w_dih_l + (size_t)3 * HDIM * HDIM,
            w_dhh_h + (size_t)3 * HDIM * HDIM, w_dhh_l + (size_t)3 * HDIM * HDIM,
            dec_bih + 3 * HDIM, dec_bhh + 3 * HDIM,
            h1h[p ^ 1], h1l[p ^ 1], h1f[p ^ 1],
            (u16*)nullptr, (u16*)nullptr, out + (size_t)t * NH);
    }
    // ---- hT = [h0 final, h1 final] (parity 0 after 40 steps) ----
    k_copyf4<<<(int)(2 * NH / 4 / 256), 256, 0, stream>>>(
        hf, out + (size_t)S_LEN * NH, (int)(2 * NH / 4));
}